// Round 14
// baseline (98.996 us; speedup 1.0000x reference)
//
#include <hip/hip_runtime.h>
#include <hip/hip_bf16.h>
#include <stdint.h>

typedef int i32x4 __attribute__((ext_vector_type(4)));

constexpr int IN_F = 1024;
constexpr int OUT_F = 1024;
constexpr int M_TOT = 8 * 4096;   // 32768 tokens
constexpr int K_TOT = 1024;
constexpr int N_TOT = 1024;

// ---------------- kernel 1: unpack ternary -> B in MFMA-fragment order (r9-verified) ----------------
// wt2 layout: [kt64(16)][col(1024)][kq(4)][kb(16)]; a wave's B-frag (col=base+(l&15),
// k = kt*64 + (l>>4)*16 ..+15) is one per-lane 16B load, 1KB contiguous per wave.
__global__ __launch_bounds__(256) void unpack_kernel(
    const int* __restrict__ packed,
    int8_t* __restrict__ wt2)          // 1 MiB
{
    const int o = blockIdx.x;
    const int k0 = threadIdx.x * 4;
    const int sh = (o >> 8) * 2;
    const int pbase = ((o & 255) << 10) + k0;
    const int4 pw = *reinterpret_cast<const int4*>(packed + pbase);
    char4 r;
    r.x = (char)(((pw.x >> sh) & 3) - 1);
    r.y = (char)(((pw.y >> sh) & 3) - 1);
    r.z = (char)(((pw.z >> sh) & 3) - 1);
    r.w = (char)(((pw.w >> sh) & 3) - 1);
    const int addr = (k0 >> 6) * 65536 + o * 64 + ((k0 >> 4) & 3) * 16 + (k0 & 15);
    *reinterpret_cast<char4*>(wt2 + addr) = r;
}

// ---------------- kernel 2: FUSED quant-to-LDS + int8 MFMA GEMM ----------------
// 256 blocks (1/CU), 512 thr (8 waves, 2/SIMD). Block owns 128 rows.
// Phase 1: quantize own rows straight into LDS q-tile (128 KiB, involution-swizzled);
// per-row scales in LDS. ONE barrier. q never touches global memory.
// Phase 2: barrier-free K-loop. A frags: ds_read_b128 from resident q-tile.
// B frags: global 16B/lane loads from fragment-ordered wt2 (L2-resident), dbuf bX/bY.
// Output as two N-halves of 512 (acc 128 VGPR each); half-0 write overlaps half-1.
// Waves: 2M x 4N; per wave 64 rows x 128 cols per half.
__global__ __launch_bounds__(512, 2) void fused_kernel(
    const float* __restrict__ x,
    const int8_t* __restrict__ wt2,
    const float* __restrict__ wscale,
    const float* __restrict__ bias,
    float* __restrict__ out)
{
    const int tid = threadIdx.x;
    const int lane = tid & 63;
    const int wid = tid >> 6;           // 0..7
    const int wr = wid >> 2;            // 0..1 (rows wr*64..)
    const int wc = wid & 3;             // 0..3 (cols wc*128.. within half)
    const int frow = lane & 15;
    const int fq = lane >> 4;           // 0..3
    const int row0 = blockIdx.x * 128;

    __shared__ int8_t qT[128 * 1024];   // 128 KiB, swizzled: chunk c -> c ^ (lrow&7)
    __shared__ float scl[128];

    // ======== phase 1: quantize 128 rows of x into LDS ========
    const float wsc = wscale[0];
    const int c8 = lane & 7;
    #pragma unroll
    for (int g = 0; g < 2; ++g) {
        const int lr = wid * 16 + g * 8 + (lane >> 3);   // local row 0..127
        const float4* xr = reinterpret_cast<const float4*>(x + (size_t)(row0 + lr) * IN_F);
        // pass 1 (HBM, coalesced: 8 lanes x 16B = 128B/row/instr): row absmax
        float m = 0.f;
        #pragma unroll 4
        for (int j = 0; j < 32; ++j) {
            const float4 v = xr[c8 + 8 * j];
            m = fmaxf(m, fmaxf(fmaxf(fabsf(v.x), fabsf(v.y)),
                               fmaxf(fabsf(v.z), fabsf(v.w))));
        }
        m = fmaxf(m, __shfl_xor(m, 1));
        m = fmaxf(m, __shfl_xor(m, 2));
        m = fmaxf(m, __shfl_xor(m, 4));
        const float a = fmaxf(m, 1e-5f);
        const float as = 127.0f / a;
        if (c8 == 0) scl[lr] = (a / 127.0f) * wsc;
        // pass 2 (L2-hot): lane owns 16B k-chunks ci = c8 + 8*jj -> ds_write_b128
        #pragma unroll 2
        for (int jj = 0; jj < 8; ++jj) {
            const int ci = c8 + 8 * jj;              // 16-i8 chunk index 0..63
            i32x4 o4;
            #pragma unroll
            for (int u = 0; u < 4; ++u) {
                const float4 v = xr[ci * 4 + u];
                const int b0 = (int)fminf(fmaxf(rintf(v.x * as), -128.f), 127.f) & 255;
                const int b1 = (int)fminf(fmaxf(rintf(v.y * as), -128.f), 127.f) & 255;
                const int b2 = (int)fminf(fmaxf(rintf(v.z * as), -128.f), 127.f) & 255;
                const int b3 = (int)fminf(fmaxf(rintf(v.w * as), -128.f), 127.f) & 255;
                o4[u] = b0 | (b1 << 8) | (b2 << 16) | (b3 << 24);
            }
            const int sc16 = ci ^ (lr & 7);
            *reinterpret_cast<i32x4*>(&qT[lr * 1024 + sc16 * 16]) = o4;
        }
    }
    __syncthreads();                     // q-tile + scales visible to all waves

    // ======== phase 2: GEMM, barrier-free ========
    // A frag: lrow = wr*64 + mf*16 + frow; chunk c = kt*4 + fq, swizzled
    auto ldA = [&](int kt, int mf) -> i32x4 {
        const int lrow = wr * 64 + mf * 16 + frow;
        const int c = kt * 4 + fq;
        return *reinterpret_cast<const i32x4*>(&qT[lrow * 1024 + (c ^ (lrow & 7)) * 16]);
    };
    // B frag base: col = half*512 + wc*128 + nf*16 + frow
    const int8_t* wbB = wt2 + (size_t)(wc * 128 + frow) * 64 + fq * 16;

    #pragma unroll 1
    for (int half = 0; half < 2; ++half) {
        const int8_t* wbH = wbB + (size_t)half * 512 * 64;
        i32x4 acc[4][8] = {};
        i32x4 bX[8], bY[8];
        #pragma unroll
        for (int nf = 0; nf < 8; ++nf)
            bX[nf] = *reinterpret_cast<const i32x4*>(wbH + 0 * 65536 + nf * 1024);
        #pragma unroll
        for (int nf = 0; nf < 8; ++nf)
            bY[nf] = *reinterpret_cast<const i32x4*>(wbH + 1 * 65536 + nf * 1024);

        #pragma unroll 1
        for (int kt = 0; kt < 16; kt += 2) {
            // even tile: bX
            {
                i32x4 aF[4];
                #pragma unroll
                for (int mf = 0; mf < 4; ++mf) aF[mf] = ldA(kt, mf);
                __builtin_amdgcn_s_setprio(1);
                #pragma unroll
                for (int mf = 0; mf < 4; ++mf)
                    #pragma unroll
                    for (int nf = 0; nf < 8; ++nf)
                        acc[mf][nf] = __builtin_amdgcn_mfma_i32_16x16x64_i8(
                            aF[mf], bX[nf], acc[mf][nf], 0, 0, 0);
                __builtin_amdgcn_s_setprio(0);
                if (kt + 2 < 16) {
                    #pragma unroll
                    for (int nf = 0; nf < 8; ++nf)
                        bX[nf] = *reinterpret_cast<const i32x4*>(
                            wbH + (size_t)(kt + 2) * 65536 + nf * 1024);
                }
            }
            // odd tile: bY
            {
                i32x4 aF[4];
                #pragma unroll
                for (int mf = 0; mf < 4; ++mf) aF[mf] = ldA(kt + 1, mf);
                __builtin_amdgcn_s_setprio(1);
                #pragma unroll
                for (int mf = 0; mf < 4; ++mf)
                    #pragma unroll
                    for (int nf = 0; nf < 8; ++nf)
                        acc[mf][nf] = __builtin_amdgcn_mfma_i32_16x16x64_i8(
                            aF[mf], bY[nf], acc[mf][nf], 0, 0, 0);
                __builtin_amdgcn_s_setprio(0);
                if (kt + 3 < 16) {
                    #pragma unroll
                    for (int nf = 0; nf < 8; ++nf)
                        bY[nf] = *reinterpret_cast<const i32x4*>(
                            wbH + (size_t)(kt + 3) * 65536 + nf * 1024);
                }
            }
        }

        // epilogue for this half: C/D 16x16 layout (col = lane&15, row = fq*4 + reg)
        #pragma unroll
        for (int mf = 0; mf < 4; ++mf) {
            #pragma unroll
            for (int j = 0; j < 4; ++j) {
                const int lrow = wr * 64 + mf * 16 + fq * 4 + j;
                const int gm = row0 + lrow;
                const float sc = scl[lrow];
                #pragma unroll
                for (int nf = 0; nf < 8; ++nf) {
                    const int gn = half * 512 + wc * 128 + nf * 16 + frow;
                    __builtin_nontemporal_store(
                        (float)acc[mf][nf][j] * sc + bias[gn],
                        &out[(size_t)gm * N_TOT + gn]);
                }
            }
        }
    }
}

extern "C" void kernel_launch(void* const* d_in, const int* in_sizes, int n_in,
                              void* d_out, int out_size, void* d_ws, size_t ws_size,
                              hipStream_t stream) {
    const float* x = (const float*)d_in[0];
    const int* packed = (const int*)d_in[1];
    const float* wscale = (const float*)d_in[2];
    const float* bias = (const float*)d_in[3];
    float* out = (float*)d_out;

    int8_t* wt2 = (int8_t*)d_ws;   // 1 MiB fragment-ordered weights

    unpack_kernel<<<OUT_F, 256, 0, stream>>>(packed, wt2);
    fused_kernel<<<M_TOT / 128, 512, 0, stream>>>(x, wt2, wscale, bias, out);
}